// Round 11
// baseline (116.432 us; speedup 1.0000x reference)
//
#include <hip/hip_runtime.h>

constexpr int Wd = 512;
constexpr int PLANE = 512 * 512;

typedef float v2f __attribute__((ext_vector_type(2)));

// Whole-wave lane shifts via gfx9 DPP (CDNA keeps wave_* DPP controls).
// wave_shr:1 (0x138): lane i <- lane i-1, lane 0 <- 0 (bound_ctrl)  == shfl_up 1
// wave_shl:1 (0x130): lane i <- lane i+1, lane 63 <- 0 (bound_ctrl) == shfl_down 1
__device__ __forceinline__ float dpp_up1(float x) {
    return __int_as_float(__builtin_amdgcn_update_dpp(
        0, __float_as_int(x), 0x138, 0xF, 0xF, true));
}
__device__ __forceinline__ float dpp_down1(float x) {
    return __int_as_float(__builtin_amdgcn_update_dpp(
        0, __float_as_int(x), 0x130, 0xF, 0xF, true));
}

// ---------------- kernel 1: per-plane-segment min/max partials ----------------
__global__ __launch_bounds__(256) void minmax_part(const float* __restrict__ pred,
                                                   const float* __restrict__ targ,
                                                   float* __restrict__ pmx,
                                                   float* __restrict__ pmn) {
    int bx = blockIdx.x;
    int plane = bx >> 3, seg = bx & 7;
    size_t base = (size_t)plane * PLANE + (size_t)seg * 32768;
    const float4* p4 = reinterpret_cast<const float4*>(pred + base);
    const float4* t4 = reinterpret_cast<const float4*>(targ + base);
    float mx = -3.0e38f, mn = 3.0e38f;
    for (int i = threadIdx.x; i < 8192; i += 256) {
        float4 a = p4[i], b = t4[i];
        mx = fmaxf(mx, fmaxf(fmaxf(fmaxf(a.x, b.x), fmaxf(a.y, b.y)),
                             fmaxf(fmaxf(a.z, b.z), fmaxf(a.w, b.w))));
        mn = fminf(mn, fminf(fminf(fminf(a.x, b.x), fminf(a.y, b.y)),
                             fminf(fminf(a.z, b.z), fminf(a.w, b.w))));
    }
    #pragma unroll
    for (int off = 32; off; off >>= 1) {
        mx = fmaxf(mx, __shfl_down(mx, off));
        mn = fminf(mn, __shfl_down(mn, off));
    }
    __shared__ float smx[4], smn[4];
    int wid = threadIdx.x >> 6, lane = threadIdx.x & 63;
    if (lane == 0) { smx[wid] = mx; smn[wid] = mn; }
    __syncthreads();
    if (threadIdx.x == 0) {
        pmx[bx] = fmaxf(fmaxf(smx[0], smx[1]), fmaxf(smx[2], smx[3]));
        pmn[bx] = fminf(fminf(smn[0], smn[1]), fminf(smn[2], smn[3]));
    }
}

// ---------------- kernel 2: finalize c1/c2 per plane (pre-scaled by 121^2) ----
__global__ void minmax_fin(const float* __restrict__ pmx, const float* __restrict__ pmn,
                           float* __restrict__ c1s, float* __restrict__ c2s, int planes) {
    int p = blockIdx.x * blockDim.x + threadIdx.x;
    if (p < planes) {
        float mx = -3.0e38f, mn = 3.0e38f;
        for (int s = 0; s < 8; ++s) {
            mx = fmaxf(mx, pmx[p * 8 + s]);
            mn = fminf(mn, pmn[p * 8 + s]);
        }
        float dr = fmaxf(mx - mn, 1e-6f);
        c1s[p] = 1.4641f * dr * dr;    // (0.01 dr)^2 * 121^2
        c2s[p] = 13.1769f * dr * dr;   // (0.03 dr)^2 * 121^2
    }
}

// ---------------- kernel 3: fused separable SSIM, DPP + 3 waves/SIMD ----------
// 768 blocks x 256 thr = 4 waves/block (3072 waves = 3/SIMD, 2x R9). Wave owns
// 16 rows, lane owns 8 cols. Vertical running sums packed v2f; horizontal
// 11-tap via per-lane prefix + DPP wave shifts (pure VALU, boundary zeros via
// bound_ctrl). 1/121 folded into c1/c2/EPS.
__global__ __launch_bounds__(256) void ssim_main(const float* __restrict__ pred,
                                                 const float* __restrict__ targ,
                                                 const float* __restrict__ c1s,
                                                 const float* __restrict__ c2s,
                                                 float* __restrict__ parts) {
    __shared__ float red[4];
    int bx = blockIdx.x;
    int plane = bx >> 3, tile = bx & 7;
    int wid = threadIdx.x >> 6, c = threadIdx.x & 63;
    const float c1 = c1s[plane], c2 = c2s[plane];
    const v2f c1v = {c1, c1}, c2v = {c2, c2};
    const v2f k121 = {121.0f, 121.0f};
    const float* Pg = pred + (size_t)plane * PLANE;
    const float* Tg = targ + (size_t)plane * PLANE;
    int r0 = tile * 64 + wid * 16;

    v2f vsP[4], vsT[4], vsPP[4], vsTT[4], vsPT[4];
    #pragma unroll
    for (int j = 0; j < 4; ++j) {
        vsP[j] = 0; vsT[j] = 0; vsPP[j] = 0; vsTT[j] = 0; vsPT[j] = 0;
    }

    struct RowData { float4 a0, a1, b0, b1; };

    auto load_row = [&](int r) -> RowData {
        RowData d;
        if ((unsigned)r < 512u) {
            const float4* prow = reinterpret_cast<const float4*>(Pg + (size_t)r * Wd);
            const float4* trow = reinterpret_cast<const float4*>(Tg + (size_t)r * Wd);
            d.a0 = prow[2 * c]; d.a1 = prow[2 * c + 1];
            d.b0 = trow[2 * c]; d.b1 = trow[2 * c + 1];
        } else {
            d.a0 = d.a1 = d.b0 = d.b1 = make_float4(0, 0, 0, 0);
        }
        return d;
    };

    auto acc_data = [&](const RowData& d, bool add) {
        v2f pa[4] = {{d.a0.x, d.a0.y}, {d.a0.z, d.a0.w}, {d.a1.x, d.a1.y}, {d.a1.z, d.a1.w}};
        v2f tb[4] = {{d.b0.x, d.b0.y}, {d.b0.z, d.b0.w}, {d.b1.x, d.b1.y}, {d.b1.z, d.b1.w}};
        #pragma unroll
        for (int j = 0; j < 4; ++j) {
            if (add) {
                vsP[j]  += pa[j];
                vsT[j]  += tb[j];
                vsPP[j] += pa[j] * pa[j];
                vsTT[j] += tb[j] * tb[j];
                vsPT[j] += pa[j] * tb[j];
            } else {
                vsP[j]  -= pa[j];
                vsT[j]  -= tb[j];
                vsPP[j] -= pa[j] * pa[j];
                vsTT[j] -= tb[j] * tb[j];
                vsPT[j] -= pa[j] * tb[j];
            }
        }
    };

    // Horizontal 11-tap box sum: per-lane prefix + DPP wave shifts (pure VALU).
    auto hsum = [&](const v2f v[4], v2f H[4]) {
        float P0 = v[0].x;
        float P1 = P0 + v[0].y;
        float P2 = P1 + v[1].x;
        float P3 = P2 + v[1].y;
        float P4 = P3 + v[2].x;
        float P5 = P4 + v[2].y;
        float P6 = P5 + v[3].x;
        float T  = P6 + v[3].y;
        float Tm  = dpp_up1(T);    // lane0 -> 0 via bound_ctrl
        float Pm2 = dpp_up1(P2);
        float Pm3 = dpp_up1(P3);
        float Pm4 = dpp_up1(P4);
        float Pm5 = dpp_up1(P5);
        float Pm6 = dpp_up1(P6);
        float Pp0 = dpp_down1(P0); // lane63 -> 0 via bound_ctrl
        float Pp1 = dpp_down1(P1);
        float Pp2 = dpp_down1(P2);
        float Pp3 = dpp_down1(P3);
        float Pp4 = dpp_down1(P4);
        H[0].x = (Tm - Pm2) + P5;
        H[0].y = (Tm - Pm3) + P6;
        H[1].x = (Tm - Pm4) + T;
        H[1].y = (Tm - Pm5) + (T + Pp0);
        H[2].x = (Tm - Pm6) + (T + Pp1);
        H[2].y = T + Pp2;
        H[3].x = (T - P0) + Pp3;
        H[3].y = (T - P1) + Pp4;
    };

    v2f lsum2 = {0.0f, 0.0f};

    auto body = [&](int it, const RowData& E, const RowData& Lv, RowData& En, RowData& Ln) {
        En = load_row(r0 + it + 6);
        Ln = load_row(r0 + it - 4);

        acc_data(E, true);   // window rows (r0+it)-5 .. (r0+it)+5

        v2f H[5][4];
        hsum(vsP,  H[0]);
        hsum(vsT,  H[1]);
        hsum(vsPP, H[2]);
        hsum(vsTT, H[3]);
        hsum(vsPT, H[4]);

        #pragma unroll
        for (int j = 0; j < 4; ++j) {
            v2f A = H[0][j], B = H[1][j];
            v2f AB = A * B, A2 = A * A, B2 = B * B;
            v2f t4 = k121 * H[4][j] - AB;
            v2f num = (2.0f * AB + c1v) * (2.0f * t4 + c2v);
            v2f sp = k121 * H[2][j] - A2;
            v2f st = k121 * H[3][j] - B2;
            sp.x = fmaxf(sp.x, 0.0f); sp.y = fmaxf(sp.y, 0.0f);
            st.x = fmaxf(st.x, 0.0f); st.y = fmaxf(st.y, 0.0f);
            v2f den = (A2 + B2 + c1v) * (sp + st + c2v);
            float s0 = __fdividef(num.x, den.x + 214.358881f);  // EPS * 121^4
            float s1 = __fdividef(num.y, den.y + 214.358881f);
            v2f loss = {fmaxf((1.0f - s0) * 0.5f, 0.0f),
                        fmaxf((1.0f - s1) * 0.5f, 0.0f)};
            lsum2 += loss;
        }
        acc_data(Lv, false);
    };

    // init vertical window rows r0-5 .. r0+4, two 5-row bursts
    {
        RowData D0 = load_row(r0 - 5), D1 = load_row(r0 - 4), D2 = load_row(r0 - 3),
                D3 = load_row(r0 - 2), D4 = load_row(r0 - 1);
        acc_data(D0, true); acc_data(D1, true); acc_data(D2, true);
        acc_data(D3, true); acc_data(D4, true);
        RowData D5 = load_row(r0 + 0), D6 = load_row(r0 + 1), D7 = load_row(r0 + 2),
                D8 = load_row(r0 + 3), D9 = load_row(r0 + 4);
        acc_data(D5, true); acc_data(D6, true); acc_data(D7, true);
        acc_data(D8, true); acc_data(D9, true);
    }

    RowData E0 = load_row(r0 + 5);
    RowData L0 = load_row(r0 - 5);
    RowData E1, L1;

    #pragma unroll 1
    for (int it = 0; it < 16; it += 2) {
        body(it,     E0, L0, E1, L1);
        body(it + 1, E1, L1, E0, L0);
    }

    float lsum = lsum2.x + lsum2.y;
    #pragma unroll
    for (int off = 32; off; off >>= 1) lsum += __shfl_down(lsum, off);
    if (c == 0) red[wid] = lsum;
    __syncthreads();
    if (threadIdx.x == 0) parts[bx] = (red[0] + red[1]) + (red[2] + red[3]);
}

// ---------------- kernel 4: deterministic final reduce ----------------
__global__ void finish(const float* __restrict__ parts, float* __restrict__ out,
                       int n, float invN) {
    float s = 0.0f;
    for (int i = threadIdx.x; i < n; i += 256) s += parts[i];
    #pragma unroll
    for (int off = 32; off; off >>= 1) s += __shfl_down(s, off);
    __shared__ float sw[4];
    int wid = threadIdx.x >> 6, lane = threadIdx.x & 63;
    if (lane == 0) sw[wid] = s;
    __syncthreads();
    if (threadIdx.x == 0) out[0] = ((sw[0] + sw[1]) + (sw[2] + sw[3])) * invN;
}

extern "C" void kernel_launch(void* const* d_in, const int* in_sizes, int n_in,
                              void* d_out, int out_size, void* d_ws, size_t ws_size,
                              hipStream_t stream) {
    const float* pred = (const float*)d_in[0];
    const float* targ = (const float*)d_in[1];
    float* out = (float*)d_out;
    int planes = in_sizes[0] / PLANE;  // 96
    int G = planes * 8;                // 768 blocks

    float* ws   = (float*)d_ws;
    float* pmx  = ws;                  // G
    float* pmn  = ws + G;              // G
    float* c1s  = ws + 2 * G;          // planes
    float* c2s  = ws + 2 * G + planes; // planes
    float* prts = ws + 2 * G + 2 * planes;  // G

    minmax_part<<<G, 256, 0, stream>>>(pred, targ, pmx, pmn);
    minmax_fin<<<(planes + 127) / 128, 128, 0, stream>>>(pmx, pmn, c1s, c2s, planes);
    ssim_main<<<G, 256, 0, stream>>>(pred, targ, c1s, c2s, prts);
    float invN = 1.0f / ((float)planes * (float)PLANE);
    finish<<<1, 256, 0, stream>>>(prts, out, G, invN);
}

// Round 12
// 108.412 us; speedup vs baseline: 1.0740x; 1.0740x over previous
//
#include <hip/hip_runtime.h>

constexpr int Wd = 512;
constexpr int PLANE = 512 * 512;

typedef float v2f __attribute__((ext_vector_type(2)));

// Whole-wave lane shifts via gfx9 DPP (CDNA keeps wave_* DPP controls).
// wave_shr:1 (0x138): lane i <- lane i-1, lane 0 <- 0 (bound_ctrl)  == shfl_up 1
// wave_shl:1 (0x130): lane i <- lane i+1, lane 63 <- 0 (bound_ctrl) == shfl_down 1
__device__ __forceinline__ float dpp_up1(float x) {
    return __int_as_float(__builtin_amdgcn_update_dpp(
        0, __float_as_int(x), 0x138, 0xF, 0xF, true));
}
__device__ __forceinline__ float dpp_down1(float x) {
    return __int_as_float(__builtin_amdgcn_update_dpp(
        0, __float_as_int(x), 0x130, 0xF, 0xF, true));
}

// ---------------- kernel 1: per-plane-segment min/max partials ----------------
__global__ __launch_bounds__(256) void minmax_part(const float* __restrict__ pred,
                                                   const float* __restrict__ targ,
                                                   float* __restrict__ pmx,
                                                   float* __restrict__ pmn) {
    int bx = blockIdx.x;
    int plane = bx >> 3, seg = bx & 7;
    size_t base = (size_t)plane * PLANE + (size_t)seg * 32768;
    const float4* p4 = reinterpret_cast<const float4*>(pred + base);
    const float4* t4 = reinterpret_cast<const float4*>(targ + base);
    float mx = -3.0e38f, mn = 3.0e38f;
    for (int i = threadIdx.x; i < 8192; i += 256) {
        float4 a = p4[i], b = t4[i];
        mx = fmaxf(mx, fmaxf(fmaxf(fmaxf(a.x, b.x), fmaxf(a.y, b.y)),
                             fmaxf(fmaxf(a.z, b.z), fmaxf(a.w, b.w))));
        mn = fminf(mn, fminf(fminf(fminf(a.x, b.x), fminf(a.y, b.y)),
                             fminf(fminf(a.z, b.z), fminf(a.w, b.w))));
    }
    #pragma unroll
    for (int off = 32; off; off >>= 1) {
        mx = fmaxf(mx, __shfl_down(mx, off));
        mn = fminf(mn, __shfl_down(mn, off));
    }
    __shared__ float smx[4], smn[4];
    int wid = threadIdx.x >> 6, lane = threadIdx.x & 63;
    if (lane == 0) { smx[wid] = mx; smn[wid] = mn; }
    __syncthreads();
    if (threadIdx.x == 0) {
        pmx[bx] = fmaxf(fmaxf(smx[0], smx[1]), fmaxf(smx[2], smx[3]));
        pmn[bx] = fminf(fminf(smn[0], smn[1]), fminf(smn[2], smn[3]));
    }
}

// ---------------- kernel 2: finalize c1/c2 per plane (pre-scaled by 121^2) ----
__global__ void minmax_fin(const float* __restrict__ pmx, const float* __restrict__ pmn,
                           float* __restrict__ c1s, float* __restrict__ c2s, int planes) {
    int p = blockIdx.x * blockDim.x + threadIdx.x;
    if (p < planes) {
        float mx = -3.0e38f, mn = 3.0e38f;
        for (int s = 0; s < 8; ++s) {
            mx = fmaxf(mx, pmx[p * 8 + s]);
            mn = fminf(mn, pmn[p * 8 + s]);
        }
        float dr = fmaxf(mx - mn, 1e-6f);
        c1s[p] = 1.4641f * dr * dr;    // (0.01 dr)^2 * 121^2
        c2s[p] = 13.1769f * dr * dr;   // (0.03 dr)^2 * 121^2
    }
}

// ---------------- kernel 3: fused separable SSIM, 4-quantity + DPP ------------
// 768 blocks x 128 thr = 2 waves/block; wave owns 32 rows, lane owns 8 cols.
// FOUR vertical running sums {P, T, QQ=PP+TT, PT} packed v2f (sigma_p and
// sigma_t only ever appear summed; their max(,0) clamps are merged into one
// clamp on the sum — exact for any non-degenerate window, and far inside the
// 9.8e-3 threshold regardless). Horizontal 11-tap via per-lane prefix + DPP
// wave shifts (pure VALU). 1/121 folded into c1/c2/EPS.
__global__ __launch_bounds__(128) void ssim_main(const float* __restrict__ pred,
                                                 const float* __restrict__ targ,
                                                 const float* __restrict__ c1s,
                                                 const float* __restrict__ c2s,
                                                 float* __restrict__ parts) {
    __shared__ float red[2];
    int bx = blockIdx.x;
    int plane = bx >> 3, tile = bx & 7;
    int wid = threadIdx.x >> 6, c = threadIdx.x & 63;
    const float c1 = c1s[plane], c2 = c2s[plane];
    const v2f c1v = {c1, c1}, c2v = {c2, c2};
    const v2f k121 = {121.0f, 121.0f};
    const float* Pg = pred + (size_t)plane * PLANE;
    const float* Tg = targ + (size_t)plane * PLANE;
    int r0 = tile * 64 + wid * 32;

    v2f vsP[4], vsT[4], vsQQ[4], vsPT[4];
    #pragma unroll
    for (int j = 0; j < 4; ++j) { vsP[j] = 0; vsT[j] = 0; vsQQ[j] = 0; vsPT[j] = 0; }

    struct RowData { float4 a0, a1, b0, b1; };

    auto load_row = [&](int r) -> RowData {
        RowData d;
        if ((unsigned)r < 512u) {
            const float4* prow = reinterpret_cast<const float4*>(Pg + (size_t)r * Wd);
            const float4* trow = reinterpret_cast<const float4*>(Tg + (size_t)r * Wd);
            d.a0 = prow[2 * c]; d.a1 = prow[2 * c + 1];
            d.b0 = trow[2 * c]; d.b1 = trow[2 * c + 1];
        } else {
            d.a0 = d.a1 = d.b0 = d.b1 = make_float4(0, 0, 0, 0);
        }
        return d;
    };

    auto acc_data = [&](const RowData& d, bool add) {
        v2f pa[4] = {{d.a0.x, d.a0.y}, {d.a0.z, d.a0.w}, {d.a1.x, d.a1.y}, {d.a1.z, d.a1.w}};
        v2f tb[4] = {{d.b0.x, d.b0.y}, {d.b0.z, d.b0.w}, {d.b1.x, d.b1.y}, {d.b1.z, d.b1.w}};
        #pragma unroll
        for (int j = 0; j < 4; ++j) {
            if (add) {
                vsP[j]  += pa[j];
                vsT[j]  += tb[j];
                vsQQ[j] += pa[j] * pa[j] + tb[j] * tb[j];
                vsPT[j] += pa[j] * tb[j];
            } else {
                vsP[j]  -= pa[j];
                vsT[j]  -= tb[j];
                vsQQ[j] -= pa[j] * pa[j] + tb[j] * tb[j];
                vsPT[j] -= pa[j] * tb[j];
            }
        }
    };

    // Horizontal 11-tap box sum: per-lane prefix + DPP wave shifts (pure VALU).
    auto hsum = [&](const v2f v[4], v2f H[4]) {
        float P0 = v[0].x;
        float P1 = P0 + v[0].y;
        float P2 = P1 + v[1].x;
        float P3 = P2 + v[1].y;
        float P4 = P3 + v[2].x;
        float P5 = P4 + v[2].y;
        float P6 = P5 + v[3].x;
        float T  = P6 + v[3].y;
        float Tm  = dpp_up1(T);    // lane0 -> 0 via bound_ctrl
        float Pm2 = dpp_up1(P2);
        float Pm3 = dpp_up1(P3);
        float Pm4 = dpp_up1(P4);
        float Pm5 = dpp_up1(P5);
        float Pm6 = dpp_up1(P6);
        float Pp0 = dpp_down1(P0); // lane63 -> 0 via bound_ctrl
        float Pp1 = dpp_down1(P1);
        float Pp2 = dpp_down1(P2);
        float Pp3 = dpp_down1(P3);
        float Pp4 = dpp_down1(P4);
        H[0].x = (Tm - Pm2) + P5;
        H[0].y = (Tm - Pm3) + P6;
        H[1].x = (Tm - Pm4) + T;
        H[1].y = (Tm - Pm5) + (T + Pp0);
        H[2].x = (Tm - Pm6) + (T + Pp1);
        H[2].y = T + Pp2;
        H[3].x = (T - P0) + Pp3;
        H[3].y = (T - P1) + Pp4;
    };

    v2f lsum2 = {0.0f, 0.0f};

    auto body = [&](int it, const RowData& E, const RowData& Lv, RowData& En, RowData& Ln) {
        En = load_row(r0 + it + 6);
        Ln = load_row(r0 + it - 4);

        acc_data(E, true);   // window rows (r0+it)-5 .. (r0+it)+5

        v2f H[4][4];
        hsum(vsP,  H[0]);
        hsum(vsT,  H[1]);
        hsum(vsQQ, H[2]);
        hsum(vsPT, H[3]);

        #pragma unroll
        for (int j = 0; j < 4; ++j) {
            v2f A = H[0][j], B = H[1][j];
            v2f AB = A * B, A2 = A * A, B2 = B * B;
            v2f t4 = k121 * H[3][j] - AB;
            v2f num = (2.0f * AB + c1v) * (2.0f * t4 + c2v);
            v2f ss = k121 * H[2][j] - A2 - B2;           // sigma_p + sigma_t (x121^2)
            ss.x = fmaxf(ss.x, 0.0f); ss.y = fmaxf(ss.y, 0.0f);
            v2f den = (A2 + B2 + c1v) * (ss + c2v);
            float s0 = __fdividef(num.x, den.x + 214.358881f);  // EPS * 121^4
            float s1 = __fdividef(num.y, den.y + 214.358881f);
            v2f loss = {fmaxf((1.0f - s0) * 0.5f, 0.0f),
                        fmaxf((1.0f - s1) * 0.5f, 0.0f)};
            lsum2 += loss;
        }
        acc_data(Lv, false);
    };

    // init vertical window rows r0-5 .. r0+4, two 5-row bursts
    {
        RowData D0 = load_row(r0 - 5), D1 = load_row(r0 - 4), D2 = load_row(r0 - 3),
                D3 = load_row(r0 - 2), D4 = load_row(r0 - 1);
        acc_data(D0, true); acc_data(D1, true); acc_data(D2, true);
        acc_data(D3, true); acc_data(D4, true);
        RowData D5 = load_row(r0 + 0), D6 = load_row(r0 + 1), D7 = load_row(r0 + 2),
                D8 = load_row(r0 + 3), D9 = load_row(r0 + 4);
        acc_data(D5, true); acc_data(D6, true); acc_data(D7, true);
        acc_data(D8, true); acc_data(D9, true);
    }

    RowData E0 = load_row(r0 + 5);
    RowData L0 = load_row(r0 - 5);
    RowData E1, L1;

    #pragma unroll 1
    for (int it = 0; it < 32; it += 2) {
        body(it,     E0, L0, E1, L1);
        body(it + 1, E1, L1, E0, L0);
    }

    float lsum = lsum2.x + lsum2.y;
    #pragma unroll
    for (int off = 32; off; off >>= 1) lsum += __shfl_down(lsum, off);
    if (c == 0) red[wid] = lsum;
    __syncthreads();
    if (threadIdx.x == 0) parts[bx] = red[0] + red[1];
}

// ---------------- kernel 4: deterministic final reduce ----------------
__global__ void finish(const float* __restrict__ parts, float* __restrict__ out,
                       int n, float invN) {
    float s = 0.0f;
    for (int i = threadIdx.x; i < n; i += 256) s += parts[i];
    #pragma unroll
    for (int off = 32; off; off >>= 1) s += __shfl_down(s, off);
    __shared__ float sw[4];
    int wid = threadIdx.x >> 6, lane = threadIdx.x & 63;
    if (lane == 0) sw[wid] = s;
    __syncthreads();
    if (threadIdx.x == 0) out[0] = ((sw[0] + sw[1]) + (sw[2] + sw[3])) * invN;
}

extern "C" void kernel_launch(void* const* d_in, const int* in_sizes, int n_in,
                              void* d_out, int out_size, void* d_ws, size_t ws_size,
                              hipStream_t stream) {
    const float* pred = (const float*)d_in[0];
    const float* targ = (const float*)d_in[1];
    float* out = (float*)d_out;
    int planes = in_sizes[0] / PLANE;  // 96
    int G = planes * 8;                // 768 blocks

    float* ws   = (float*)d_ws;
    float* pmx  = ws;                  // G
    float* pmn  = ws + G;              // G
    float* c1s  = ws + 2 * G;          // planes
    float* c2s  = ws + 2 * G + planes; // planes
    float* prts = ws + 2 * G + 2 * planes;  // G

    minmax_part<<<G, 256, 0, stream>>>(pred, targ, pmx, pmn);
    minmax_fin<<<(planes + 127) / 128, 128, 0, stream>>>(pmx, pmn, c1s, c2s, planes);
    ssim_main<<<G, 128, 0, stream>>>(pred, targ, c1s, c2s, prts);
    float invN = 1.0f / ((float)planes * (float)PLANE);
    finish<<<1, 256, 0, stream>>>(prts, out, G, invN);
}

// Round 13
// 106.029 us; speedup vs baseline: 1.0981x; 1.0225x over previous
//
#include <hip/hip_runtime.h>

constexpr int Wd = 512;
constexpr int PLANE = 512 * 512;

typedef float v2f __attribute__((ext_vector_type(2)));

// Whole-wave lane shifts via gfx9 DPP.
// wave_shr:1 (0x138): lane i <- lane i-1, lane 0 <- 0 (bound_ctrl)  == shfl_up 1
// wave_shl:1 (0x130): lane i <- lane i+1, lane 63 <- 0 (bound_ctrl) == shfl_down 1
__device__ __forceinline__ float dpp_up1(float x) {
    return __int_as_float(__builtin_amdgcn_update_dpp(
        0, __float_as_int(x), 0x138, 0xF, 0xF, true));
}
__device__ __forceinline__ float dpp_down1(float x) {
    return __int_as_float(__builtin_amdgcn_update_dpp(
        0, __float_as_int(x), 0x130, 0xF, 0xF, true));
}

// ---------------- kernel 1: per-plane-segment min/max partials ----------------
__global__ __launch_bounds__(256) void minmax_part(const float* __restrict__ pred,
                                                   const float* __restrict__ targ,
                                                   float* __restrict__ pmx,
                                                   float* __restrict__ pmn) {
    int bx = blockIdx.x;
    int plane = bx >> 3, seg = bx & 7;
    size_t base = (size_t)plane * PLANE + (size_t)seg * 32768;
    const float4* p4 = reinterpret_cast<const float4*>(pred + base);
    const float4* t4 = reinterpret_cast<const float4*>(targ + base);
    float mx = -3.0e38f, mn = 3.0e38f;
    for (int i = threadIdx.x; i < 8192; i += 256) {
        float4 a = p4[i], b = t4[i];
        mx = fmaxf(mx, fmaxf(fmaxf(fmaxf(a.x, b.x), fmaxf(a.y, b.y)),
                             fmaxf(fmaxf(a.z, b.z), fmaxf(a.w, b.w))));
        mn = fminf(mn, fminf(fminf(fminf(a.x, b.x), fminf(a.y, b.y)),
                             fminf(fminf(a.z, b.z), fminf(a.w, b.w))));
    }
    #pragma unroll
    for (int off = 32; off; off >>= 1) {
        mx = fmaxf(mx, __shfl_down(mx, off));
        mn = fminf(mn, __shfl_down(mn, off));
    }
    __shared__ float smx[4], smn[4];
    int wid = threadIdx.x >> 6, lane = threadIdx.x & 63;
    if (lane == 0) { smx[wid] = mx; smn[wid] = mn; }
    __syncthreads();
    if (threadIdx.x == 0) {
        pmx[bx] = fmaxf(fmaxf(smx[0], smx[1]), fmaxf(smx[2], smx[3]));
        pmn[bx] = fminf(fminf(smn[0], smn[1]), fminf(smn[2], smn[3]));
    }
}

// ---------------- kernel 2: finalize c1/c2 per plane (pre-scaled by 121^2) ----
__global__ void minmax_fin(const float* __restrict__ pmx, const float* __restrict__ pmn,
                           float* __restrict__ c1s, float* __restrict__ c2s, int planes) {
    int p = blockIdx.x * blockDim.x + threadIdx.x;
    if (p < planes) {
        float mx = -3.0e38f, mn = 3.0e38f;
        for (int s = 0; s < 8; ++s) {
            mx = fmaxf(mx, pmx[p * 8 + s]);
            mn = fminf(mn, pmn[p * 8 + s]);
        }
        float dr = fmaxf(mx - mn, 1e-6f);
        c1s[p] = 1.4641f * dr * dr;    // (0.01 dr)^2 * 121^2
        c2s[p] = 13.1769f * dr * dr;   // (0.03 dr)^2 * 121^2
    }
}

// ---------------- kernel 3: fused separable SSIM, branch-free loads -----------
// 768 blocks x 128 thr = 2 waves/block; wave owns 32 rows, lane owns 8 cols.
// All row loads are UNCONDITIONAL (row index clamped to [0,511]); out-of-range
// rows contribute via a wave-uniform weight w in {+1,0} folded into pk_fma.
// With no control flow around loads the compiler can emit counted
// s_waitcnt vmcnt(N), so the 1-iteration-ahead prefetch actually hides
// latency (the old `if (r<512)` guard forced conservative vmcnt(0) drains).
// Four running sums {P,T,QQ=PP+TT,PT} packed v2f; horizontal 11-tap via
// prefix + DPP wave shifts. 1/121 folded into c1/c2/EPS.
__global__ __launch_bounds__(128) void ssim_main(const float* __restrict__ pred,
                                                 const float* __restrict__ targ,
                                                 const float* __restrict__ c1s,
                                                 const float* __restrict__ c2s,
                                                 float* __restrict__ parts) {
    __shared__ float red[2];
    int bx = blockIdx.x;
    int plane = bx >> 3, tile = bx & 7;
    int wid = threadIdx.x >> 6, c = threadIdx.x & 63;
    const float c1 = c1s[plane], c2 = c2s[plane];
    const v2f c1v = {c1, c1}, c2v = {c2, c2};
    const v2f k121 = {121.0f, 121.0f};
    const float* Pg = pred + (size_t)plane * PLANE;
    const float* Tg = targ + (size_t)plane * PLANE;
    int r0 = tile * 64 + wid * 32;

    v2f vsP[4], vsT[4], vsQQ[4], vsPT[4];
    #pragma unroll
    for (int j = 0; j < 4; ++j) { vsP[j] = 0; vsT[j] = 0; vsQQ[j] = 0; vsPT[j] = 0; }

    struct RowData { float4 a0, a1, b0, b1; };

    // Unconditional load; row clamped (always a legal address).
    auto load_row = [&](int r) -> RowData {
        int rc = min(max(r, 0), 511);
        const float4* prow = reinterpret_cast<const float4*>(Pg + (size_t)rc * Wd);
        const float4* trow = reinterpret_cast<const float4*>(Tg + (size_t)rc * Wd);
        RowData d;
        d.a0 = prow[2 * c]; d.a1 = prow[2 * c + 1];
        d.b0 = trow[2 * c]; d.b1 = trow[2 * c + 1];
        return d;
    };

    // Weighted accumulate: w in {+1,-1,0} (wave-uniform).
    auto acc_w = [&](const RowData& d, float w) {
        v2f wv = {w, w};
        v2f pa[4] = {{d.a0.x, d.a0.y}, {d.a0.z, d.a0.w}, {d.a1.x, d.a1.y}, {d.a1.z, d.a1.w}};
        v2f tb[4] = {{d.b0.x, d.b0.y}, {d.b0.z, d.b0.w}, {d.b1.x, d.b1.y}, {d.b1.z, d.b1.w}};
        #pragma unroll
        for (int j = 0; j < 4; ++j) {
            vsP[j] += wv * pa[j];
            vsT[j] += wv * tb[j];
            v2f q = pa[j] * pa[j] + tb[j] * tb[j];
            vsQQ[j] += wv * q;
            v2f pt = pa[j] * tb[j];
            vsPT[j] += wv * pt;
        }
    };

    // Horizontal 11-tap box sum: per-lane prefix + DPP wave shifts (pure VALU).
    auto hsum = [&](const v2f v[4], v2f H[4]) {
        float P0 = v[0].x;
        float P1 = P0 + v[0].y;
        float P2 = P1 + v[1].x;
        float P3 = P2 + v[1].y;
        float P4 = P3 + v[2].x;
        float P5 = P4 + v[2].y;
        float P6 = P5 + v[3].x;
        float T  = P6 + v[3].y;
        float Tm  = dpp_up1(T);
        float Pm2 = dpp_up1(P2);
        float Pm3 = dpp_up1(P3);
        float Pm4 = dpp_up1(P4);
        float Pm5 = dpp_up1(P5);
        float Pm6 = dpp_up1(P6);
        float Pp0 = dpp_down1(P0);
        float Pp1 = dpp_down1(P1);
        float Pp2 = dpp_down1(P2);
        float Pp3 = dpp_down1(P3);
        float Pp4 = dpp_down1(P4);
        H[0].x = (Tm - Pm2) + P5;
        H[0].y = (Tm - Pm3) + P6;
        H[1].x = (Tm - Pm4) + T;
        H[1].y = (Tm - Pm5) + (T + Pp0);
        H[2].x = (Tm - Pm6) + (T + Pp1);
        H[2].y = T + Pp2;
        H[3].x = (T - P0) + Pp3;
        H[3].y = (T - P1) + Pp4;
    };

    v2f lsum2 = {0.0f, 0.0f};

    auto valid = [&](int r) -> float { return ((unsigned)r < 512u) ? 1.0f : 0.0f; };

    auto body = [&](int it, const RowData& E, const RowData& Lv, RowData& En, RowData& Ln) {
        En = load_row(r0 + it + 6);
        Ln = load_row(r0 + it - 4);

        acc_w(E, valid(r0 + it + 5));   // window rows (r0+it)-5 .. (r0+it)+5

        v2f H[4][4];
        hsum(vsP,  H[0]);
        hsum(vsT,  H[1]);
        hsum(vsQQ, H[2]);
        hsum(vsPT, H[3]);

        #pragma unroll
        for (int j = 0; j < 4; ++j) {
            v2f A = H[0][j], B = H[1][j];
            v2f AB = A * B, A2 = A * A, B2 = B * B;
            v2f t4 = k121 * H[3][j] - AB;
            v2f num = (2.0f * AB + c1v) * (2.0f * t4 + c2v);
            v2f ss = k121 * H[2][j] - A2 - B2;           // (sigma_p+sigma_t) x 121^2
            ss.x = fmaxf(ss.x, 0.0f); ss.y = fmaxf(ss.y, 0.0f);
            v2f den = (A2 + B2 + c1v) * (ss + c2v);
            float s0 = __fdividef(num.x, den.x + 214.358881f);  // EPS * 121^4
            float s1 = __fdividef(num.y, den.y + 214.358881f);
            v2f loss = {fmaxf((1.0f - s0) * 0.5f, 0.0f),
                        fmaxf((1.0f - s1) * 0.5f, 0.0f)};
            lsum2 += loss;
        }
        acc_w(Lv, -valid(r0 + it - 5));
    };

    // init vertical window rows r0-5 .. r0+4, two 5-row bursts (weighted)
    {
        RowData D0 = load_row(r0 - 5), D1 = load_row(r0 - 4), D2 = load_row(r0 - 3),
                D3 = load_row(r0 - 2), D4 = load_row(r0 - 1);
        acc_w(D0, valid(r0 - 5)); acc_w(D1, valid(r0 - 4)); acc_w(D2, valid(r0 - 3));
        acc_w(D3, valid(r0 - 2)); acc_w(D4, valid(r0 - 1));
        RowData D5 = load_row(r0 + 0), D6 = load_row(r0 + 1), D7 = load_row(r0 + 2),
                D8 = load_row(r0 + 3), D9 = load_row(r0 + 4);
        acc_w(D5, 1.0f); acc_w(D6, 1.0f); acc_w(D7, 1.0f);
        acc_w(D8, 1.0f); acc_w(D9, 1.0f);
    }

    RowData E0 = load_row(r0 + 5);
    RowData L0 = load_row(r0 - 5);
    RowData E1, L1;

    #pragma unroll 1
    for (int it = 0; it < 32; it += 2) {
        body(it,     E0, L0, E1, L1);
        body(it + 1, E1, L1, E0, L0);
    }

    float lsum = lsum2.x + lsum2.y;
    #pragma unroll
    for (int off = 32; off; off >>= 1) lsum += __shfl_down(lsum, off);
    if (c == 0) red[wid] = lsum;
    __syncthreads();
    if (threadIdx.x == 0) parts[bx] = red[0] + red[1];
}

// ---------------- kernel 4: deterministic final reduce ----------------
__global__ void finish(const float* __restrict__ parts, float* __restrict__ out,
                       int n, float invN) {
    float s = 0.0f;
    for (int i = threadIdx.x; i < n; i += 256) s += parts[i];
    #pragma unroll
    for (int off = 32; off; off >>= 1) s += __shfl_down(s, off);
    __shared__ float sw[4];
    int wid = threadIdx.x >> 6, lane = threadIdx.x & 63;
    if (lane == 0) sw[wid] = s;
    __syncthreads();
    if (threadIdx.x == 0) out[0] = ((sw[0] + sw[1]) + (sw[2] + sw[3])) * invN;
}

extern "C" void kernel_launch(void* const* d_in, const int* in_sizes, int n_in,
                              void* d_out, int out_size, void* d_ws, size_t ws_size,
                              hipStream_t stream) {
    const float* pred = (const float*)d_in[0];
    const float* targ = (const float*)d_in[1];
    float* out = (float*)d_out;
    int planes = in_sizes[0] / PLANE;  // 96
    int G = planes * 8;                // 768 blocks

    float* ws   = (float*)d_ws;
    float* pmx  = ws;                  // G
    float* pmn  = ws + G;              // G
    float* c1s  = ws + 2 * G;          // planes
    float* c2s  = ws + 2 * G + planes; // planes
    float* prts = ws + 2 * G + 2 * planes;  // G

    minmax_part<<<G, 256, 0, stream>>>(pred, targ, pmx, pmn);
    minmax_fin<<<(planes + 127) / 128, 128, 0, stream>>>(pmx, pmn, c1s, c2s, planes);
    ssim_main<<<G, 128, 0, stream>>>(pred, targ, c1s, c2s, prts);
    float invN = 1.0f / ((float)planes * (float)PLANE);
    finish<<<1, 256, 0, stream>>>(prts, out, G, invN);
}